// Round 17
// baseline (37.409 us; speedup 1.0000x reference)
//
#include <hip/hip_runtime.h>

typedef float f4v __attribute__((ext_vector_type(4)));

#define DD 128
#define HH 256
#define WW 256
#define OD 127
#define SLICE_F (HH*WW)
#define CHUNK 8
#define TEN_B 5120          // 5 rows x 1KB per tensor
#define BUF_B 10240         // pred(5KB) + targ(5KB)
#define WAVE_B 20480        // 2 buffers per wave
#define AS1 __attribute__((address_space(1)))
#define AS3 __attribute__((address_space(3)))

#define WAITS() asm volatile("s_waitcnt vmcnt(10)" ::: "memory")
#define WAIT0() asm volatile("s_waitcnt vmcnt(0)"  ::: "memory")
#define SB0()   __builtin_amdgcn_sched_barrier(0)

struct Sl { f4v uu2[4]; f4v vv2[4]; f4v ps[4]; };

// stage this wave's private 5 pred + 5 targ rows of one slice (10 x gload_lds)
__device__ __forceinline__ void stage_slice(const float* __restrict__ pB,
                                            const float* __restrict__ tB,
                                            int s, char* lb, int h0w, int lane)
{
    const size_t so = ((size_t)s << 16) + (size_t)(lane << 2);
    #pragma unroll
    for (int r = 0; r < 5; ++r) {
        const int grow = min(h0w + r, HH - 1);
        const float* gp = pB + so + ((size_t)grow << 8);
        const float* gt = tB + so + ((size_t)grow << 8);
        __builtin_amdgcn_global_load_lds((const AS1 void*)gp,
            (AS3 void*)(lb + r * 1024 + lane * 16), 16, 0, 0);
        __builtin_amdgcn_global_load_lds((const AS1 void*)gt,
            (AS3 void*)(lb + TEN_B + r * 1024 + lane * 16), 16, 0, 0);
    }
}

__device__ __forceinline__ void make_sl(const char* lb, int lane, Sl& S)
{
    const float* sp = (const float*)lb;
    const float* st = (const float*)(lb + TEN_B);
    const int co = lane << 2;
    const float4 p0 = *(const float4*)(sp + co);
    const float4 p1 = *(const float4*)(sp + co + 256);
    const float4 p2 = *(const float4*)(sp + co + 512);
    const float4 p3 = *(const float4*)(sp + co + 768);
    const float4 p4 = *(const float4*)(sp + co + 1024);
    const float4 t0 = *(const float4*)(st + co);
    const float4 t1 = *(const float4*)(st + co + 256);
    const float4 t2 = *(const float4*)(st + co + 512);
    const float4 t3 = *(const float4*)(st + co + 768);
    const float4 t4 = *(const float4*)(st + co + 1024);

    float e0x=__expf(p0.x), e1x=__expf(p1.x), e2x=__expf(p2.x), e3x=__expf(p3.x), e4x=__expf(p4.x);
    float e0y=__expf(p0.y), e1y=__expf(p1.y), e2y=__expf(p2.y), e3y=__expf(p3.y), e4y=__expf(p4.y);
    float e0z=__expf(p0.z), e1z=__expf(p1.z), e2z=__expf(p2.z), e3z=__expf(p3.z), e4z=__expf(p4.z);
    float e0w=__expf(p0.w), e1w=__expf(p1.w), e2w=__expf(p2.w), e3w=__expf(p3.w), e4w=__expf(p4.w);

    f4v Wx = {e0x*e1x, e1x*e2x, e2x*e3x, e3x*e4x};
    f4v Wy = {e0y*e1y, e1y*e2y, e2y*e3y, e3y*e4y};
    f4v Wz = {e0z*e1z, e1z*e2z, e2z*e3z, e3z*e4z};
    f4v Ww = {e0w*e1w, e1w*e2w, e2w*e3w, e3w*e4w};
    f4v Qx = {(1.f+e0x)*(1.f+e1x), (1.f+e1x)*(1.f+e2x), (1.f+e2x)*(1.f+e3x), (1.f+e3x)*(1.f+e4x)};
    f4v Qy = {(1.f+e0y)*(1.f+e1y), (1.f+e1y)*(1.f+e2y), (1.f+e2y)*(1.f+e3y), (1.f+e3y)*(1.f+e4y)};
    f4v Qz = {(1.f+e0z)*(1.f+e1z), (1.f+e1z)*(1.f+e2z), (1.f+e2z)*(1.f+e3z), (1.f+e3z)*(1.f+e4z)};
    f4v Qw = {(1.f+e0w)*(1.f+e1w), (1.f+e1w)*(1.f+e2w), (1.f+e2w)*(1.f+e3w), (1.f+e3w)*(1.f+e4w)};

    f4v W4, Q4;
    W4.x = __shfl_down(Wx.x, 1); W4.y = __shfl_down(Wx.y, 1);
    W4.z = __shfl_down(Wx.z, 1); W4.w = __shfl_down(Wx.w, 1);
    Q4.x = __shfl_down(Qx.x, 1); Q4.y = __shfl_down(Qx.y, 1);
    Q4.z = __shfl_down(Qx.z, 1); Q4.w = __shfl_down(Qx.w, 1);

    S.uu2[0]=Wx*Wy; S.uu2[1]=Wy*Wz; S.uu2[2]=Wz*Ww; S.uu2[3]=Ww*W4;
    S.vv2[0]=Qx*Qy; S.vv2[1]=Qy*Qz; S.vv2[2]=Qz*Qw; S.vv2[3]=Qw*Q4;

    f4v cx = {t0.x+t1.x, t1.x+t2.x, t2.x+t3.x, t3.x+t4.x};
    f4v cy = {t0.y+t1.y, t1.y+t2.y, t2.y+t3.y, t3.y+t4.y};
    f4v cz = {t0.z+t1.z, t1.z+t2.z, t2.z+t3.z, t3.z+t4.z};
    f4v cw = {t0.w+t1.w, t1.w+t2.w, t2.w+t3.w, t3.w+t4.w};
    f4v c4;
    c4.x = __shfl_down(cx.x, 1); c4.y = __shfl_down(cx.y, 1);
    c4.z = __shfl_down(cx.z, 1); c4.w = __shfl_down(cx.w, 1);
    S.ps[0]=cx+cy; S.ps[1]=cy+cz; S.ps[2]=cz+cw; S.ps[3]=cw+c4;
}

__device__ __forceinline__ void do_cubes(const Sl& P, const Sl& C,
        const f4v vAll, const f4v v3,
        f4v& aFG, f4v& aF255, f4v& aBG, f4v& aBG0, f4v& aSFA,
        f4v& c255, f4v& c0, f4v& cMN)
{
    #pragma unroll
    for (int j = 0; j < 4; ++j) {
        f4v E = P.uu2[j] * C.uu2[j];
        f4v Q = P.vv2[j] * C.vv2[j];
        f4v vj = (j == 3) ? v3 : vAll;
        f4v r;
        r.x = __builtin_amdgcn_rcpf(Q.x); r.y = __builtin_amdgcn_rcpf(Q.y);
        r.z = __builtin_amdgcn_rcpf(Q.z); r.w = __builtin_amdgcn_rcpf(Q.w);
        r *= vj;
        f4v fg = E * r;
        f4v pop = P.ps[j] + C.ps[j];      // exact 0..8
        f4v i255, i0, mn;
        i255.x = fmaxf(pop.x - 7.f, 0.f); i255.y = fmaxf(pop.y - 7.f, 0.f);
        i255.z = fmaxf(pop.z - 7.f, 0.f); i255.w = fmaxf(pop.w - 7.f, 0.f);
        i0.x   = fmaxf(1.f - pop.x, 0.f); i0.y   = fmaxf(1.f - pop.y, 0.f);
        i0.z   = fmaxf(1.f - pop.z, 0.f); i0.w   = fmaxf(1.f - pop.w, 0.f);
        mn.x   = 4.f - fabsf(pop.x - 4.f); mn.y = 4.f - fabsf(pop.y - 4.f);
        mn.z   = 4.f - fabsf(pop.z - 4.f); mn.w = 4.f - fabsf(pop.w - 4.f);
        mn *= vj;
        aFG  += fg;
        aBG  += r;
        aF255 = fg * i255 + aF255;
        aBG0  = r  * i0   + aBG0;
        c255  = i255 * vj + c255;
        c0    = i0   * vj + c0;
        aSFA  = (fg + r) * mn + aSFA;
        cMN  += mn;
    }
}

// per-wave depth-1 pipeline step, NO barriers anywhere in the loop
#define LAYER(SRC, DST)                                                        \
    do {                                                                       \
        if (t + 2 <= NT) {                                                     \
            stage_slice(pB, tB, d0 + t + 2, wb + (t & 1) * BUF_B, h0w, lane);  \
            WAITS();        /* 10 outstanding = the stage just issued */       \
        } else {                                                               \
            WAIT0();                                                           \
        }                                                                      \
        SB0();                                                                 \
        make_sl(wb + ((t + 1) & 1) * BUF_B, lane, DST);                        \
        do_cubes(SRC, DST, vAll, v3, aFG, aF255, aBG, aBG0, aSFA, c255, c0, cMN); \
    } while (0)

// ws: [512 blocks][4 waves][8 partial sums] -- fully overwritten, no pre-zero
__global__ __launch_bounds__(256, 2)
void loss_main(const float* __restrict__ preds,
               const float* __restrict__ targets,
               float* __restrict__ ws)
{
    __shared__ __align__(16) char smem[4 * WAVE_B];   // 80 KB exactly -> 2 blocks/CU

    const int lane = threadIdx.x & 63;
    const int wv   = threadIdx.x >> 6;
    char* wb = smem + wv * WAVE_B;

    // bijective XCD-chunked swizzle: 512 blocks, 64 contiguous per XCD
    const int nid = ((blockIdx.x & 7) << 6) + (blockIdx.x >> 3);
    const int x = nid & 15;            // h-slab (16 rows)
    const int y = (nid >> 4) & 15;     // d-chunk
    const int b = nid >> 8;            // batch

    const int h0w = (x << 4) + (wv << 2);   // this wave's first cube row (4 rows)
    const int d0  = y << 3;
    const int NT  = min(CHUNK, OD - d0);    // 8 (last chunk: 7)

    const float* pB = preds   + (size_t)b * DD * SLICE_F;
    const float* tB = targets + (size_t)b * DD * SLICE_F;

    const float v63 = (lane == 63) ? 0.f : 1.f;
    f4v vAll;
    vAll.x = (h0w     < HH - 1) ? 1.f : 0.f;
    vAll.y = (h0w + 1 < HH - 1) ? 1.f : 0.f;
    vAll.z = (h0w + 2 < HH - 1) ? 1.f : 0.f;
    vAll.w = (h0w + 3 < HH - 1) ? 1.f : 0.f;
    const f4v v3 = vAll * v63;

    f4v aFG={0,0,0,0}, aF255=aFG, aBG=aFG, aBG0=aFG, aSFA=aFG;
    f4v c255=aFG, c0=aFG, cMN=aFG;

    // prologue: stage slices 0,1 into this wave's two buffers
    stage_slice(pB, tB, d0,     wb,         h0w, lane);
    stage_slice(pB, tB, d0 + 1, wb + BUF_B, h0w, lane);
    WAITS();                               // slice 0 landed (slice 1 in flight)
    SB0();

    Sl A, B;
    make_sl(wb, lane, A);                  // slice d0 -> A

    int t = 0;
    for (;;) {
        LAYER(A, B);
        if (++t >= NT) break;
        LAYER(B, A);
        if (++t >= NT) break;
    }

    float acc[8];
    acc[0] = (aFG.x  + aFG.y)  + (aFG.z  + aFG.w);
    acc[1] = (aF255.x+ aF255.y)+ (aF255.z+ aF255.w);
    acc[2] = (c255.x + c255.y) + (c255.z + c255.w);
    acc[3] = (aBG.x  + aBG.y)  + (aBG.z  + aBG.w);
    acc[4] = (aBG0.x + aBG0.y) + (aBG0.z + aBG0.w);
    acc[5] = (c0.x   + c0.y)   + (c0.z   + c0.w);
    acc[6] = (aSFA.x + aSFA.y) + (aSFA.z + aSFA.w);
    acc[7] = (cMN.x  + cMN.y)  + (cMN.z  + cMN.w);
    #pragma unroll
    for (int i = 0; i < 8; ++i) {
        float v = acc[i];
        #pragma unroll
        for (int off = 32; off > 0; off >>= 1) v += __shfl_xor(v, off);
        acc[i] = v;
    }
    float mine = acc[0];
    mine = (lane == 1) ? acc[1] : mine;
    mine = (lane == 2) ? acc[2] : mine;
    mine = (lane == 3) ? acc[3] : mine;
    mine = (lane == 4) ? acc[4] : mine;
    mine = (lane == 5) ? acc[5] : mine;
    mine = (lane == 6) ? acc[6] : mine;
    mine = (lane == 7) ? acc[7] : mine;
    if (lane < 8)
        ws[(nid * 4 + wv) * 8 + lane] = mine;   // per-wave partial, no block red
}

__global__ void loss_final(const float* __restrict__ ws, float* __restrict__ out)
{
    __shared__ float fin[256];
    __shared__ float S[16];
    const int tid = threadIdx.x;          // 256
    const int s = tid & 7, k = tid >> 3;  // k 0..31
    const int b2 = k >> 4;                // wave-partials 0..1023 batch0, 1024.. batch1
    float v = 0.f;
    #pragma unroll 4
    for (int j = 0; j < 64; ++j) {
        int g = b2 * 1024 + (k & 15) * 64 + j;
        v += ws[g * 8 + s];
    }
    fin[tid] = v;
    __syncthreads();
    if (tid < 16) {
        const int bb = tid >> 3, s2 = tid & 7;
        float q = 0.f;
        #pragma unroll
        for (int k2 = 0; k2 < 16; ++k2) q += fin[(((bb << 4) + k2) << 3) | s2];
        S[tid] = q;
    }
    __syncthreads();
    if (tid == 0) {
        const float eps = 1e-5f;
        float dice = 0.f;
        #pragma unroll
        for (int bb = 0; bb < 2; ++bb) {
            const float* q = S + bb * 8;
            float fg_dice = (2.f*q[1] + eps) / (q[0] + q[2] + eps);
            float bg_dice = (2.f*q[4] + eps) / (q[3] + q[5] + eps);
            float q6 = 0.5f * q[6];          // area = 0.5*min(pop,8-pop)
            float q7 = 0.5f * q[7];
            float ss = q7 - q6;              // sum(surf*area)
            float sf_dice = (2.f*ss + eps) / (ss + q7 + eps);
            dice += fg_dice + bg_dice + sf_dice;
        }
        out[0] = 1.f - dice * (1.f/6.f);
    }
}

extern "C" void kernel_launch(void* const* d_in, const int* in_sizes, int n_in,
                              void* d_out, int out_size, void* d_ws, size_t ws_size,
                              hipStream_t stream)
{
    const float* preds   = (const float*)d_in[0];
    const float* targets = (const float*)d_in[1];
    // d_in[2] power / d_in[3] kernel / d_in[4] area are analytic -- baked in
    float* ws = (float*)d_ws;

    loss_main<<<512, 256, 0, stream>>>(preds, targets, ws);   // 2 blocks/CU exact
    loss_final<<<1, 256, 0, stream>>>(ws, (float*)d_out);
}

// Round 18
// 32.647 us; speedup vs baseline: 1.1459x; 1.1459x over previous
//
#include <hip/hip_runtime.h>

typedef float f2 __attribute__((ext_vector_type(2)));

#define DD 128
#define HH 256
#define WW 256
#define OD 127
#define SLICE_F (HH*WW)
#define CHUNK 16
#define TEN_B 9216          // 9 rows x 1KB per tensor
#define SLOT_B 18432        // pred 9 rows + targ 9 rows
#define NBUF 4
#define AS1 __attribute__((address_space(1)))
#define AS3 __attribute__((address_space(3)))

// per-wave counted waits (waves 0,1 issue 5 loads/slice; waves 2,3 issue 4)
#define WAITP() do { if (wv < 2) asm volatile("s_waitcnt vmcnt(10)" ::: "memory"); \
                     else        asm volatile("s_waitcnt vmcnt(8)"  ::: "memory"); } while (0)
#define WAIT1() do { if (wv < 2) asm volatile("s_waitcnt vmcnt(5)"  ::: "memory"); \
                     else        asm volatile("s_waitcnt vmcnt(4)"  ::: "memory"); } while (0)
#define WAIT0() asm volatile("s_waitcnt vmcnt(0)" ::: "memory")

struct Sl { f2 uu2[4]; f2 vv2[4]; f2 ps[4]; };

// stage one slice: 9 pred rows + 9 targ rows -> one LDS slot (18 loads, split 5/5/4/4)
__device__ __forceinline__ void stage_slice(const float* __restrict__ pB,
                                            const float* __restrict__ tB,
                                            int s, char* lb, int h0, int wv, int lane)
{
    #pragma unroll
    for (int i = 0; i < 5; ++i) {
        const int L = i * 4 + wv;                 // 0..19, wave-uniform predicate
        if (L < 18) {
            const int T = (L >= 9) ? 1 : 0;       // 0=pred 1=targ
            const int r = L - T * 9;              // row slot 0..8
            const int grow = min(h0 + r, HH - 1);
            const float* g = (T ? tB : pB)
                           + ((size_t)s << 16) + ((size_t)grow << 8) + (lane << 2);
            void* l = lb + T * TEN_B + r * 1024 + lane * 16;
            __builtin_amdgcn_global_load_lds((const AS1 void*)g, (AS3 void*)l, 16, 0, 0);
        }
    }
}

__device__ __forceinline__ void make_sl(const char* lb, int wv, int lane, Sl& S)
{
    const float* sp = (const float*)lb;
    const float* st = (const float*)(lb + TEN_B);
    const int ro = ((wv << 1) << 8) + (lane << 2);   // row 2*wv, col lane*4
    const float4 p0 = *(const float4*)(sp + ro);
    const float4 p1 = *(const float4*)(sp + ro + 256);
    const float4 p2 = *(const float4*)(sp + ro + 512);
    const float4 t0 = *(const float4*)(st + ro);
    const float4 t1 = *(const float4*)(st + ro + 256);
    const float4 t2 = *(const float4*)(st + ro + 512);

    float u0x=__expf(p0.x), u0y=__expf(p0.y), u0z=__expf(p0.z), u0w=__expf(p0.w);
    float u1x=__expf(p1.x), u1y=__expf(p1.y), u1z=__expf(p1.z), u1w=__expf(p1.w);
    float u2x=__expf(p2.x), u2y=__expf(p2.y), u2z=__expf(p2.z), u2w=__expf(p2.w);

    f2 uA0 = {u0x,u1x}, uB0 = {u1x,u2x};
    f2 uA1 = {u0y,u1y}, uB1 = {u1y,u2y};
    f2 uA2 = {u0z,u1z}, uB2 = {u1z,u2z};
    f2 uA3 = {u0w,u1w}, uB3 = {u1w,u2w};

    f2 W0 = uA0*uB0, W1 = uA1*uB1, W2 = uA2*uB2, W3 = uA3*uB3;
    f2 Q0 = (uA0+1.f)*(uB0+1.f);
    f2 Q1 = (uA1+1.f)*(uB1+1.f);
    f2 Q2 = (uA2+1.f)*(uB2+1.f);
    f2 Q3 = (uA3+1.f)*(uB3+1.f);
    f2 W4, Q4;
    W4.x = __shfl_down(W0.x, 1); W4.y = __shfl_down(W0.y, 1);
    Q4.x = __shfl_down(Q0.x, 1); Q4.y = __shfl_down(Q0.y, 1);

    S.uu2[0]=W0*W1; S.uu2[1]=W1*W2; S.uu2[2]=W2*W3; S.uu2[3]=W3*W4;
    S.vv2[0]=Q0*Q1; S.vv2[1]=Q1*Q2; S.vv2[2]=Q2*Q3; S.vv2[3]=Q3*Q4;

    f2 cs0 = {t0.x+t1.x, t1.x+t2.x};
    f2 cs1 = {t0.y+t1.y, t1.y+t2.y};
    f2 cs2 = {t0.z+t1.z, t1.z+t2.z};
    f2 cs3 = {t0.w+t1.w, t1.w+t2.w};
    f2 cs4; cs4.x = __shfl_down(cs0.x, 1); cs4.y = __shfl_down(cs0.y, 1);
    S.ps[0]=cs0+cs1; S.ps[1]=cs1+cs2; S.ps[2]=cs2+cs3; S.ps[3]=cs3+cs4;
}

__device__ __forceinline__ void do_cubes(const Sl& P, const Sl& C,
        const f2 vAll, const f2 v3,
        f2& aFG, f2& aF255, f2& aBG, f2& aBG0, f2& aSFA,
        f2& c255, f2& c0, f2& cMN)
{
    #pragma unroll
    for (int j = 0; j < 4; ++j) {
        f2 E = P.uu2[j] * C.uu2[j];
        f2 Q = P.vv2[j] * C.vv2[j];
        f2 vj = (j == 3) ? v3 : vAll;
        f2 r; r.x = __builtin_amdgcn_rcpf(Q.x); r.y = __builtin_amdgcn_rcpf(Q.y);
        r *= vj;
        f2 fg = E * r;
        f2 pop = P.ps[j] + C.ps[j];      // exact 0..8
        f2 i255, i0, mn;
        i255.x = fmaxf(pop.x - 7.f, 0.f); i255.y = fmaxf(pop.y - 7.f, 0.f);
        i0.x   = fmaxf(1.f - pop.x, 0.f); i0.y   = fmaxf(1.f - pop.y, 0.f);
        mn.x   = 4.f - fabsf(pop.x - 4.f); mn.y = 4.f - fabsf(pop.y - 4.f);
        mn *= vj;
        aFG  += fg;
        aBG  += r;
        aF255 = fg * i255 + aF255;
        aBG0  = r  * i0   + aBG0;
        c255  = i255 * vj + c255;
        c0    = i0   * vj + c0;
        aSFA  = (fg + r) * mn + aSFA;
        cMN  += mn;
    }
}

// shared depth-2 pipeline step: stage before barrier, counted waits (never drain mid-loop)
#define LAYER(SRC, DST)                                                        \
    do {                                                                       \
        if (t + 3 <= NT) {                                                     \
            stage_slice(pB, tB, d0 + t + 3, smem + sw * SLOT_B, h0, wv, lane); \
            WAITP();   /* own loads of t+2,t+3 outstanding; t+1 landed */      \
        } else if (t + 2 <= NT) {                                              \
            WAIT1();   /* only t+2 outstanding */                              \
        } else {                                                               \
            WAIT0();                                                           \
        }                                                                      \
        __builtin_amdgcn_s_barrier();                                          \
        __builtin_amdgcn_sched_barrier(0);                                     \
        make_sl(smem + sr * SLOT_B, wv, lane, DST);                            \
        do_cubes(SRC, DST, vAll, v3, aFG, aF255, aBG, aBG0, aSFA, c255, c0, cMN); \
        sr = (sr + 1) & 3;                                                     \
        sw = (sw + 1) & 3;                                                     \
    } while (0)

// ws: [512 blocks][8 partial sums] -- fully overwritten every call, no pre-zero
__global__ __launch_bounds__(256, 2)
void loss_main(const float* __restrict__ preds,
               const float* __restrict__ targets,
               float* __restrict__ ws)
{
    __shared__ __align__(16) char smem[NBUF * SLOT_B];   // 72 KB shared slots
    __shared__ float red[32];

    const int lane = threadIdx.x & 63;
    const int wv   = threadIdx.x >> 6;

    // bijective XCD-chunked swizzle: 512 blocks, 64 contiguous per XCD
    const int nid = ((blockIdx.x & 7) << 6) + (blockIdx.x >> 3);
    const int x = nid & 31;            // h-slab
    const int y = (nid >> 5) & 7;      // d-chunk
    const int b = nid >> 8;            // batch

    const int h0 = x << 3;                  // block's 8 cube rows
    const int d0 = y << 4;
    const int NT = min(CHUNK, OD - d0);     // 16 (last chunk: 15)

    const float* pB = preds   + (size_t)b * DD * SLICE_F;
    const float* tB = targets + (size_t)b * DD * SLICE_F;

    const int   myrow = h0 + (wv << 1);
    const float rv1 = (myrow + 1 < HH - 1) ? 1.f : 0.f;
    const float v63 = (lane == 63) ? 0.f : 1.f;
    const f2 vAll = {1.f, rv1};
    const f2 v3   = {v63, v63 * rv1};

    f2 aFG={0,0}, aF255={0,0}, aBG={0,0}, aBG0={0,0}, aSFA={0,0};
    f2 c255={0,0}, c0={0,0}, cMN={0,0};

    // prologue: stage slices 0,1,2 into slots 0,1,2
    stage_slice(pB, tB, d0,     smem,             h0, wv, lane);
    stage_slice(pB, tB, d0 + 1, smem + SLOT_B,    h0, wv, lane);
    stage_slice(pB, tB, d0 + 2, smem + 2*SLOT_B,  h0, wv, lane);
    WAITP();                               // slice 0 landed (1,2 in flight)
    __builtin_amdgcn_s_barrier();
    __builtin_amdgcn_sched_barrier(0);

    Sl A, B;
    make_sl(smem, wv, lane, A);            // slice d0 -> A

    int sr = 1, sw = 3;   // read slot of slice t+1; write slot of slice t+3
    int t = 0;
    for (;;) {
        LAYER(A, B);
        if (++t >= NT) break;
        LAYER(B, A);
        if (++t >= NT) break;
    }

    float acc[8] = {aFG.x+aFG.y, aF255.x+aF255.y, c255.x+c255.y,
                    aBG.x+aBG.y, aBG0.x+aBG0.y,   c0.x+c0.y,
                    aSFA.x+aSFA.y, cMN.x+cMN.y};
    #pragma unroll
    for (int i = 0; i < 8; ++i) {
        float v = acc[i];
        #pragma unroll
        for (int off = 32; off > 0; off >>= 1) v += __shfl_xor(v, off);
        acc[i] = v;
    }
    float mine = acc[0];
    mine = (lane == 1) ? acc[1] : mine;
    mine = (lane == 2) ? acc[2] : mine;
    mine = (lane == 3) ? acc[3] : mine;
    mine = (lane == 4) ? acc[4] : mine;
    mine = (lane == 5) ? acc[5] : mine;
    mine = (lane == 6) ? acc[6] : mine;
    mine = (lane == 7) ? acc[7] : mine;
    if (lane < 8) red[wv * 8 + lane] = mine;
    __syncthreads();
    if (wv == 0 && lane < 8)
        ws[nid * 8 + lane] = red[lane] + red[8 + lane] + red[16 + lane] + red[24 + lane];
}

__global__ void loss_final(const float* __restrict__ ws, float* __restrict__ out)
{
    __shared__ float part[16][17];
    __shared__ float S[16];
    const int tid = threadIdx.x;          // 256
    const int c = tid >> 4, sub = tid & 15;
    const int bb = c >> 3, s = c & 7;
    float v = 0.f;
    #pragma unroll 4
    for (int k = 0; k < 16; ++k) {
        int nid = bb * 256 + sub * 16 + k;
        v += ws[nid * 8 + s];
    }
    part[c][sub] = v;
    __syncthreads();
    if (tid < 16) {
        float q = 0.f;
        #pragma unroll
        for (int i = 0; i < 16; ++i) q += part[tid][i];
        S[tid] = q;
    }
    __syncthreads();
    if (tid == 0) {
        const float eps = 1e-5f;
        float dice = 0.f;
        #pragma unroll
        for (int b2 = 0; b2 < 2; ++b2) {
            const float* q = S + b2 * 8;
            float fg_dice = (2.f*q[1] + eps) / (q[0] + q[2] + eps);
            float bg_dice = (2.f*q[4] + eps) / (q[3] + q[5] + eps);
            float q6 = 0.5f * q[6];          // area = 0.5*min(pop,8-pop)
            float q7 = 0.5f * q[7];
            float ss = q7 - q6;              // sum(surf*area)
            float sf_dice = (2.f*ss + eps) / (ss + q7 + eps);
            dice += fg_dice + bg_dice + sf_dice;
        }
        out[0] = 1.f - dice * (1.f/6.f);
    }
}

extern "C" void kernel_launch(void* const* d_in, const int* in_sizes, int n_in,
                              void* d_out, int out_size, void* d_ws, size_t ws_size,
                              hipStream_t stream)
{
    const float* preds   = (const float*)d_in[0];
    const float* targets = (const float*)d_in[1];
    // d_in[2] power / d_in[3] kernel / d_in[4] area are analytic -- baked in
    float* ws = (float*)d_ws;

    loss_main<<<512, 256, 0, stream>>>(preds, targets, ws);   // 2 blocks/CU exact
    loss_final<<<1, 256, 0, stream>>>(ws, (float*)d_out);
}